// Round 1
// 240.324 us; speedup vs baseline: 1.0142x; 1.0142x over previous
//
#include <hip/hip_runtime.h>
#include <stdint.h>

#define S_LEN 2048
#define NH 12
#define DM 768
#define DK 64
#define NB 2
#define MROWS (NB * S_LEN)  // 4096

typedef __attribute__((ext_vector_type(8))) short short8;
typedef __attribute__((ext_vector_type(4))) short s16x4;
typedef __attribute__((ext_vector_type(4))) float f32x4;
typedef __attribute__((ext_vector_type(4))) uint32_t u32x4;

__device__ __forceinline__ unsigned short bf16rne(float f) {
    union { float f; uint32_t u; } v; v.f = f;
    return (unsigned short)((v.u + 0x7FFFu + ((v.u >> 16) & 1u)) >> 16);
}

__device__ __forceinline__ uint32_t cvtpk(float lo, float hi) {
    uint32_t r;
    asm("v_cvt_pk_bf16_f32 %0, %1, %2" : "=v"(r) : "v"(lo), "v"(hi));
    return r;
}

// ---------------- prep: fp32 -> bf16 for q,k,v ----------------
__global__ __launch_bounds__(256) void cvt_kernel(
        const float* __restrict__ q, const float* __restrict__ k, const float* __restrict__ v,
        unsigned short* __restrict__ qb, unsigned short* __restrict__ kb, unsigned short* __restrict__ vb) {
    const float* src = (blockIdx.y == 0) ? q : (blockIdx.y == 1) ? k : v;
    unsigned short* dst = (blockIdx.y == 0) ? qb : (blockIdx.y == 1) ? kb : vb;
    int i = (blockIdx.x * 256 + threadIdx.x) * 4;
    float4 x = *(const float4*)(src + i);
    uint32_t lo = (uint32_t)bf16rne(x.x) | ((uint32_t)bf16rne(x.y) << 16);
    uint32_t hi = (uint32_t)bf16rne(x.z) | ((uint32_t)bf16rne(x.w) << 16);
    uint2 o = make_uint2(lo, hi);
    *(uint2*)(dst + i) = o;
}

// ---------------- prep: weights -> bf16, B^T layout [N][K] ----------------
__global__ __launch_bounds__(256) void wtrans_kernel(
        const float* __restrict__ Wq, const float* __restrict__ Wk,
        const float* __restrict__ Wv, const float* __restrict__ Wo,
        unsigned short* __restrict__ WqT, unsigned short* __restrict__ WkT,
        unsigned short* __restrict__ WvT, unsigned short* __restrict__ WoT) {
    int which = blockIdx.y;
    const float* W = (which == 0) ? Wq : (which == 1) ? Wk : (which == 2) ? Wv : Wo;
    unsigned short* WT = (which == 0) ? WqT : (which == 1) ? WkT : (which == 2) ? WvT : WoT;
    int idx = blockIdx.x * 256 + threadIdx.x;  // 768*768
    int n = idx / DM, kd = idx % DM;
    float val;
    if (which < 3) { int h = n >> 6, kk = n & 63; val = W[(h * DM + kd) * DK + kk]; }
    else          { val = W[kd * DM + n]; }
    WT[idx] = bf16rne(val);
}

// ---------------- prep: pack mask into bits ----------------
__global__ __launch_bounds__(256) void mask_pack(const int* __restrict__ mask, uint32_t* __restrict__ pm) {
    int tid = blockIdx.x * 256 + threadIdx.x;  // 2*2048*2048 elems
    int m = mask[tid];
    unsigned long long bm = __ballot(m != 0);
    if ((threadIdx.x & 63) == 0) {
        *(unsigned long long*)(pm + (tid >> 5)) = bm;
    }
}

// ---------------- GEMM core (m97-style): global_load_lds width-16 staging ----------------
__device__ __forceinline__ void gemm_core(const unsigned short* __restrict__ A,
                                          const unsigned short* __restrict__ BT,
                                          unsigned short* As, unsigned short* Bs,
                                          f32x4 (&acc)[4][4]) {
    const int tid = threadIdx.x;
    const int lane = tid & 63, wid = tid >> 6;
    const int ww = wid & 1, wh = wid >> 1;
    const int quad = lane >> 4, l16 = lane & 15;
    const int lr = lane >> 2;        // row within 16-row chunk
    const int lc = (lane & 3) * 8;   // col offset in shorts
    typedef __attribute__((address_space(1))) const unsigned int* gp1;
    typedef __attribute__((address_space(3))) unsigned int* lp3;
    const unsigned short* Ag = A + (size_t)(wid * 32 + lr) * DM + lc;
    const unsigned short* Bg = BT + (size_t)(wid * 32 + lr) * DM + lc;
    unsigned short* Al = &As[wid * 32 * 32];
    unsigned short* Bl = &Bs[wid * 32 * 32];
    for (int kt = 0; kt < DM; kt += 32) {
        __syncthreads();
        __builtin_amdgcn_global_load_lds((gp1)(const void*)(Ag + kt),            (lp3)(void*)Al,             16, 0, 0);
        __builtin_amdgcn_global_load_lds((gp1)(const void*)(Ag + 16 * DM + kt),  (lp3)(void*)(Al + 16 * 32), 16, 0, 0);
        __builtin_amdgcn_global_load_lds((gp1)(const void*)(Bg + kt),            (lp3)(void*)Bl,             16, 0, 0);
        __builtin_amdgcn_global_load_lds((gp1)(const void*)(Bg + 16 * DM + kt),  (lp3)(void*)(Bl + 16 * 32), 16, 0, 0);
        __syncthreads();
        short8 af[4], bf[4];
#pragma unroll
        for (int i = 0; i < 4; ++i) af[i] = *(const short8*)&As[(wh * 64 + i * 16 + l16) * 32 + quad * 8];
#pragma unroll
        for (int j = 0; j < 4; ++j) bf[j] = *(const short8*)&Bs[(ww * 64 + j * 16 + l16) * 32 + quad * 8];
#pragma unroll
        for (int i = 0; i < 4; ++i)
#pragma unroll
            for (int j = 0; j < 4; ++j)
                acc[i][j] = __builtin_amdgcn_mfma_f32_16x16x32_bf16(af[i], bf[j], acc[i][j], 0, 0, 0);
    }
}

// ---------------- projections: q,k -> [M, H*64] bf16 ; v -> vhT[b,h,d,s] bf16 ----------------
__global__ __launch_bounds__(256) void proj_gemm(
        const unsigned short* __restrict__ qb, const unsigned short* __restrict__ kb,
        const unsigned short* __restrict__ vb,
        const unsigned short* __restrict__ WqT, const unsigned short* __restrict__ WkT,
        const unsigned short* __restrict__ WvT,
        unsigned short* __restrict__ qh, unsigned short* __restrict__ kh,
        unsigned short* __restrict__ vhT) {
    __shared__ __align__(16) unsigned short As[128 * 32];
    __shared__ __align__(16) unsigned short Bs[128 * 32];
    const int z = blockIdx.z;
    const unsigned short* A = (z == 0) ? qb : (z == 1) ? kb : vb;
    const unsigned short* BT = (z == 0) ? WqT : (z == 1) ? WkT : WvT;
    f32x4 acc[4][4] = {};
    gemm_core(A + (size_t)blockIdx.x * 128 * DM, BT + (size_t)blockIdx.y * 128 * DM, As, Bs, acc);

    const int tid = threadIdx.x;
    const int lane = tid & 63, wid = tid >> 6;
    const int ww = wid & 1, wh = wid >> 1;
    const int quad = lane >> 4, l16 = lane & 15;
    const int row0 = blockIdx.x * 128 + wh * 64;
    const int col0 = blockIdx.y * 128 + ww * 64;
    if (z < 2) {
        unsigned short* C = z ? kh : qh;
#pragma unroll
        for (int i = 0; i < 4; ++i)
#pragma unroll
            for (int j = 0; j < 4; ++j)
#pragma unroll
                for (int r = 0; r < 4; ++r)
                    C[(size_t)(row0 + i * 16 + quad * 4 + r) * DM + col0 + j * 16 + l16] = bf16rne(acc[i][j][r]);
    } else {
#pragma unroll
        for (int i = 0; i < 4; ++i)
#pragma unroll
            for (int j = 0; j < 4; ++j) {
                int row = row0 + i * 16 + quad * 4;  // = b*2048 + s, 4 consecutive s
                int col = col0 + j * 16 + l16;       // = h*64 + d
                int bb = row >> 11, s = row & 2047;
                int hh = col >> 6, d = col & 63;
                uint32_t lo = (uint32_t)bf16rne(acc[i][j][0]) | ((uint32_t)bf16rne(acc[i][j][1]) << 16);
                uint32_t hi = (uint32_t)bf16rne(acc[i][j][2]) | ((uint32_t)bf16rne(acc[i][j][3]) << 16);
                uint2 o = make_uint2(lo, hi);
                *(uint2*)&vhT[(size_t)((bb * NH + hh) * DK + d) * S_LEN + s] = o;
            }
    }
}

// ---------------- flash attention: swapped QK^T -> lane-local P (no LDS round-trip) ----------------
// QK^T computed as mfma(K,Q) => C[key][q], q = lane&15, key = 16*cb + 4*quad + r.
// V is staged with bit-permuted key columns (key bits [k5 k4 k3 k2 k1 k0] stored at LDS pos
// [k5 k3 k2 k4 k1 k0]) so the PV B-operand (P^T[k][q]) is exactly the registers each lane
// already holds: pf[h'][2c+t] = cvt_pk(e[2h'+c][2t], e[2h'+c][2t+1]). Zero cross-lane ops.
// T14: next tile's K/V global loads issued right after the staging barrier (hide HBM under compute).
// Output lands transposed (q = lane&15) -> one-shot per-wave LDS bounce reusing Ks/Vs for coalesced stores.
__global__ __launch_bounds__(256) void attn_kernel(
        const unsigned short* __restrict__ qh, const unsigned short* __restrict__ kh,
        const unsigned short* __restrict__ vhT, const uint32_t* __restrict__ pm,
        unsigned short* __restrict__ pob, float* __restrict__ lsb) {
    const int qt = blockIdx.x, h = blockIdx.y;
    const int b = blockIdx.z >> 1, ks = blockIdx.z & 1;
    const int tid = threadIdx.x, w = tid >> 6, lane = tid & 63;
    const int quad = lane >> 4, l16 = lane & 15;
    __shared__ __align__(16) unsigned short SMEM[2 * 64 * 72];  // Ks | Vs ; reused as Os in epilogue
    unsigned short* Ks = SMEM;
    unsigned short* Vs = SMEM + 64 * 72;

    const int qrow0 = qt * 128 + w * 32;
    // Q as B-frags: col q = l16, dims quad*8..
    short8 qf[2][2];
#pragma unroll
    for (int mi = 0; mi < 2; ++mi) {
        const size_t qbase = (size_t)(b * S_LEN + qrow0 + mi * 16 + l16) * DM + h * DK;
        qf[mi][0] = *(const short8*)&qh[qbase + quad * 8];
        qf[mi][1] = *(const short8*)&qh[qbase + 32 + quad * 8];
    }
    // ones A-frag (only row m=0 is 1.0): lsum = ones x P via MFMA, lands in row 0 (quad0 lanes)
    short8 of = {};
    if (l16 == 0) {
#pragma unroll
        for (int j = 0; j < 8; ++j) of[j] = (short)0x3F80;
    }

    f32x4 out_t[2][4] = {};  // [mi][c2]: C[d][q], d = c2*16 + quad*4 + r, q = l16
    f32x4 outl[2] = {};

    // staging: 256 threads, 64 rows x 64 cols, 16 shorts/thread
    const int srow = tid >> 2, scol = (tid & 3) << 4;
    const unsigned short* Kg = kh + (size_t)b * S_LEN * DM + h * DK;
    const unsigned short* Vg = vhT + (size_t)((b * NH + h) * DK) * S_LEN;
    const float SCL = 0.18033688011112042f;  // 0.125 * log2(e)
    const float FM = 12.0f;                  // fixed exponent offset (softmax scale-invariant)
    const int kt0 = ks * (S_LEN / 2);
    const int vb0 = srow * 72 + ((scol & 32) | ((scol & 16) >> 2));  // permuted V dest base

    short8 kr0, kr1, vr0, vr1;
    // prologue prefetch (T14): tile kt0
    kr0 = *(const short8*)&Kg[(size_t)(kt0 + srow) * DM + scol];
    kr1 = *(const short8*)&Kg[(size_t)(kt0 + srow) * DM + scol + 8];
    vr0 = *(const short8*)&Vg[(size_t)srow * S_LEN + kt0 + scol];
    vr1 = *(const short8*)&Vg[(size_t)srow * S_LEN + kt0 + scol + 8];

    for (int kt = kt0; kt < kt0 + S_LEN / 2; kt += 64) {
        __syncthreads();  // all waves done reading previous tile
        *(short8*)&Ks[srow * 72 + scol] = kr0;
        *(short8*)&Ks[srow * 72 + scol + 8] = kr1;
        *(s16x4*)&Vs[vb0]      = __builtin_shufflevector(vr0, vr0, 0, 1, 2, 3);
        *(s16x4*)&Vs[vb0 + 8]  = __builtin_shufflevector(vr0, vr0, 4, 5, 6, 7);
        *(s16x4*)&Vs[vb0 + 16] = __builtin_shufflevector(vr1, vr1, 0, 1, 2, 3);
        *(s16x4*)&Vs[vb0 + 24] = __builtin_shufflevector(vr1, vr1, 4, 5, 6, 7);
        __syncthreads();  // tile visible
        {   // prefetch next tile (last iter reads stay inside workspace; values unused)
            const int kn = kt + 64;
            kr0 = *(const short8*)&Kg[(size_t)(kn + srow) * DM + scol];
            kr1 = *(const short8*)&Kg[(size_t)(kn + srow) * DM + scol + 8];
            vr0 = *(const short8*)&Vg[(size_t)srow * S_LEN + kn + scol];
            vr1 = *(const short8*)&Vg[(size_t)srow * S_LEN + kn + scol + 8];
        }
        // mask words: one uint2 per mi, row = q of this lane
        uint2 mw[2];
#pragma unroll
        for (int mi = 0; mi < 2; ++mi)
            mw[mi] = *(const uint2*)&pm[(size_t)(b * S_LEN + qrow0 + mi * 16 + l16) * 64 + (kt >> 5)];

        // QK^T (swapped) + exp + mask + in-lane pack to PV B-frag words
        u32x4 pf32[2][2];
#pragma unroll
        for (int cb = 0; cb < 4; ++cb) {
            short8 kf0 = *(const short8*)&Ks[(cb * 16 + l16) * 72 + quad * 8];
            short8 kf1 = *(const short8*)&Ks[(cb * 16 + l16) * 72 + 32 + quad * 8];
#pragma unroll
            for (int mi = 0; mi < 2; ++mi) {
                f32x4 zz = {0.f, 0.f, 0.f, 0.f};
                zz = __builtin_amdgcn_mfma_f32_16x16x32_bf16(kf0, qf[mi][0], zz, 0, 0, 0);
                zz = __builtin_amdgcn_mfma_f32_16x16x32_bf16(kf1, qf[mi][1], zz, 0, 0, 0);
                uint32_t mword = (cb & 2) ? mw[mi].y : mw[mi].x;
                float e[4];
#pragma unroll
                for (int r = 0; r < 4; ++r) {
                    float ev = __builtin_amdgcn_exp2f(fmaf(zz[r], SCL, -FM));
                    int32_t mneg = __builtin_amdgcn_sbfe((int32_t)mword, ((cb & 1) << 4) + quad * 4 + r, 1);
                    e[r] = __uint_as_float(__float_as_uint(ev) & (uint32_t)mneg);
                }
                pf32[mi][cb >> 1][(cb & 1) * 2 + 0] = cvtpk(e[0], e[1]);
                pf32[mi][cb >> 1][(cb & 1) * 2 + 1] = cvtpk(e[2], e[3]);
            }
        }
        short8 pf[2][2];
#pragma unroll
        for (int mi = 0; mi < 2; ++mi) {
            pf[mi][0] = __builtin_bit_cast(short8, pf32[mi][0]);
            pf[mi][1] = __builtin_bit_cast(short8, pf32[mi][1]);
        }

        __builtin_amdgcn_s_setprio(1);
#pragma unroll
        for (int c2 = 0; c2 < 4; ++c2) {
            short8 vf0 = *(const short8*)&Vs[(c2 * 16 + l16) * 72 + quad * 8];
            short8 vf1 = *(const short8*)&Vs[(c2 * 16 + l16) * 72 + 32 + quad * 8];
#pragma unroll
            for (int mi = 0; mi < 2; ++mi) {
                out_t[mi][c2] = __builtin_amdgcn_mfma_f32_16x16x32_bf16(vf0, pf[mi][0], out_t[mi][c2], 0, 0, 0);
                out_t[mi][c2] = __builtin_amdgcn_mfma_f32_16x16x32_bf16(vf1, pf[mi][1], out_t[mi][c2], 0, 0, 0);
            }
        }
#pragma unroll
        for (int mi = 0; mi < 2; ++mi) {
            outl[mi] = __builtin_amdgcn_mfma_f32_16x16x32_bf16(of, pf[mi][0], outl[mi], 0, 0, 0);
            outl[mi] = __builtin_amdgcn_mfma_f32_16x16x32_bf16(of, pf[mi][1], outl[mi], 0, 0, 0);
        }
        __builtin_amdgcn_s_setprio(0);
    }

    const int pz = b * 2 + ks;
    // lsum: C[0][q=l16] lives in quad0 lanes, reg 0
    if (quad == 0) {
#pragma unroll
        for (int mi = 0; mi < 2; ++mi)
            lsb[((size_t)pz * NH + h) * S_LEN + qrow0 + mi * 16 + l16] = outl[mi][0];
    }

    // epilogue: transpose out via per-wave LDS region (reuse SMEM), then coalesced global stores
    __syncthreads();  // all waves done with Ks/Vs
    unsigned short* Os = SMEM + w * (32 * 72);
#pragma unroll
    for (int mi = 0; mi < 2; ++mi)
#pragma unroll
        for (int c2 = 0; c2 < 4; ++c2) {
            uint2 pw2;
            pw2.x = cvtpk(out_t[mi][c2][0], out_t[mi][c2][1]);
            pw2.y = cvtpk(out_t[mi][c2][2], out_t[mi][c2][3]);
            *(uint2*)&Os[(mi * 16 + l16) * 72 + c2 * 16 + quad * 4] = pw2;
        }
    // same-wave RAW only (per-wave buffer): compiler lgkmcnt handles
    const int ql = lane >> 1, hf = lane & 1;
    const int qg = qrow0 + ql;
    const size_t orow = ((size_t)pz * S_LEN + qg) * DM + h * DK + hf * 32;
#pragma unroll
    for (int k2 = 0; k2 < 4; ++k2)
        *(short8*)&pob[orow + k2 * 8] = *(const short8*)&Os[ql * 72 + hf * 32 + k2 * 8];
}

// ---------------- merge the two K-chunk partials -> ao bf16 ----------------
__global__ __launch_bounds__(256) void merge_kernel(const unsigned short* __restrict__ pob,
                                                    const float* __restrict__ lsb,
                                                    unsigned short* __restrict__ ao) {
    int t = blockIdx.x * 256 + threadIdx.x;   // 4096*192 threads, 4 elems each
    int sg = t / 192;                          // b*S + s
    int c = (t - sg * 192) * 4;                // col in [0,768)
    int b = sg >> 11, s = sg & 2047, h = c >> 6;
    float l = lsb[((size_t)(b * 2) * NH + h) * S_LEN + s] +
              lsb[((size_t)(b * 2 + 1) * NH + h) * S_LEN + s];
    float rl = 1.f / fmaxf(l, 1e-37f);
    uint2 a0 = *(const uint2*)&pob[((size_t)(b * 2) * S_LEN + s) * DM + c];
    uint2 a1 = *(const uint2*)&pob[((size_t)(b * 2 + 1) * S_LEN + s) * DM + c];
    float f0 = __uint_as_float((a0.x & 0xFFFFu) << 16) + __uint_as_float((a1.x & 0xFFFFu) << 16);
    float f1 = __uint_as_float((a0.x >> 16) << 16)     + __uint_as_float((a1.x >> 16) << 16);
    float f2 = __uint_as_float((a0.y & 0xFFFFu) << 16) + __uint_as_float((a1.y & 0xFFFFu) << 16);
    float f3 = __uint_as_float((a0.y >> 16) << 16)     + __uint_as_float((a1.y >> 16) << 16);
    uint32_t lo = (uint32_t)bf16rne(f0 * rl) | ((uint32_t)bf16rne(f1 * rl) << 16);
    uint32_t hi = (uint32_t)bf16rne(f2 * rl) | ((uint32_t)bf16rne(f3 * rl) << 16);
    uint2 o = make_uint2(lo, hi);
    *(uint2*)&ao[(size_t)sg * DM + c] = o;
}

// ---------------- output projection: fp32 store ----------------
__global__ __launch_bounds__(256) void out_gemm(const unsigned short* __restrict__ ao,
                                                const unsigned short* __restrict__ WoT,
                                                float* __restrict__ C) {
    __shared__ __align__(16) unsigned short As[128 * 32];
    __shared__ __align__(16) unsigned short Bs[128 * 32];
    f32x4 acc[4][4] = {};
    gemm_core(ao + (size_t)blockIdx.x * 128 * DM, WoT + (size_t)blockIdx.y * 128 * DM, As, Bs, acc);
    const int tid = threadIdx.x;
    const int lane = tid & 63, wid = tid >> 6;
    const int ww = wid & 1, wh = wid >> 1;
    const int quad = lane >> 4, l16 = lane & 15;
    const int row0 = blockIdx.x * 128 + wh * 64;
    const int col0 = blockIdx.y * 128 + ww * 64;
#pragma unroll
    for (int i = 0; i < 4; ++i)
#pragma unroll
        for (int j = 0; j < 4; ++j)
#pragma unroll
            for (int r = 0; r < 4; ++r)
                C[(size_t)(row0 + i * 16 + quad * 4 + r) * DM + col0 + j * 16 + l16] = acc[i][j][r];
}

extern "C" void kernel_launch(void* const* d_in, const int* in_sizes, int n_in,
                              void* d_out, int out_size, void* d_ws, size_t ws_size,
                              hipStream_t stream) {
    const float* q = (const float*)d_in[0];
    const float* k = (const float*)d_in[1];
    const float* v = (const float*)d_in[2];
    const int* mask = (const int*)d_in[3];
    const float* Wq = (const float*)d_in[4];
    const float* Wk = (const float*)d_in[5];
    const float* Wv = (const float*)d_in[6];
    const float* Wo = (const float*)d_in[7];
    float* out = (float*)d_out;

    char* ws = (char*)d_ws;
    size_t off = 0;
    auto alloc = [&](size_t bytes) {
        void* p = ws + off;
        off += (bytes + 255) & ~(size_t)255;
        return p;
    };
    const size_t MAT = (size_t)MROWS * DM * 2;      // 6291456 B
    const size_t WMAT = (size_t)DM * DM * 2;        // 1179648 B
    unsigned short* qb  = (unsigned short*)alloc(MAT);
    unsigned short* kb  = (unsigned short*)alloc(MAT);
    unsigned short* vb  = (unsigned short*)alloc(MAT);
    unsigned short* WqT = (unsigned short*)alloc(WMAT);
    unsigned short* WkT = (unsigned short*)alloc(WMAT);
    unsigned short* WvT = (unsigned short*)alloc(WMAT);
    unsigned short* WoT = (unsigned short*)alloc(WMAT);
    unsigned short* qh  = (unsigned short*)alloc(MAT);
    unsigned short* kh  = (unsigned short*)alloc(MAT);
    unsigned short* vhT = (unsigned short*)alloc(MAT);
    unsigned short* ao  = (unsigned short*)alloc(MAT);
    uint32_t* pmask     = (uint32_t*)alloc((size_t)NB * S_LEN * 64 * 4);

    // K-split partials overlay the qb/kb/vb region (dead after proj_gemm):
    // pob: 4 * S * DM bf16 = 12.58 MB (fits in qb+kb), lsb: 4*NH*S fp32 = 0.39 MB (in vb)
    unsigned short* pob = (unsigned short*)ws;
    float* lsb = (float*)(ws + (size_t)4 * S_LEN * DM * 2);

    cvt_kernel<<<dim3(3072, 3), 256, 0, stream>>>(q, k, v, qb, kb, vb);
    wtrans_kernel<<<dim3(2304, 4), 256, 0, stream>>>(Wq, Wk, Wv, Wo, WqT, WkT, WvT, WoT);
    mask_pack<<<dim3(32768), 256, 0, stream>>>(mask, pmask);
    proj_gemm<<<dim3(32, 6, 3), 256, 0, stream>>>(qb, kb, vb, WqT, WkT, WvT, qh, kh, vhT);
    attn_kernel<<<dim3(16, 12, 4), 256, 0, stream>>>(qh, kh, vhT, pmask, pob, lsb);
    merge_kernel<<<dim3(3072), 256, 0, stream>>>(pob, lsb, ao);
    out_gemm<<<dim3(32, 6), 256, 0, stream>>>(ao, WoT, out);
}

// Round 2
// 231.591 us; speedup vs baseline: 1.0524x; 1.0377x over previous
//
#include <hip/hip_runtime.h>
#include <stdint.h>

#define S_LEN 2048
#define NH 12
#define DM 768
#define DK 64
#define NB 2
#define MROWS (NB * S_LEN)  // 4096

typedef __attribute__((ext_vector_type(8))) short short8;
typedef __attribute__((ext_vector_type(4))) float f32x4;
typedef __attribute__((ext_vector_type(4))) uint32_t u32x4;

__device__ __forceinline__ unsigned short bf16rne(float f) {
    union { float f; uint32_t u; } v; v.f = f;
    return (unsigned short)((v.u + 0x7FFFu + ((v.u >> 16) & 1u)) >> 16);
}

__device__ __forceinline__ uint32_t cvtpk(float lo, float hi) {
    uint32_t r;
    asm("v_cvt_pk_bf16_f32 %0, %1, %2" : "=v"(r) : "v"(lo), "v"(hi));
    return r;
}

// ---------------- prep (fused): weight transpose + mask bit-pack ----------------
// bx < 9216: wtrans (which = bx/2304). bx >= 9216: mask pack, 8 elems/thread, byte store
// (byte t holds mask bits for elements 8t..8t+7, LSB-first == ballot layout).
__global__ __launch_bounds__(256) void prep_kernel(
        const float* __restrict__ Wq, const float* __restrict__ Wk,
        const float* __restrict__ Wv, const float* __restrict__ Wo,
        const int* __restrict__ mask,
        unsigned short* __restrict__ WqT, unsigned short* __restrict__ WkT,
        unsigned short* __restrict__ WvT, unsigned short* __restrict__ WoT,
        uint32_t* __restrict__ pm) {
    int bx = blockIdx.x;
    if (bx < 9216) {
        int which = bx / 2304;
        const float* W = (which == 0) ? Wq : (which == 1) ? Wk : (which == 2) ? Wv : Wo;
        unsigned short* WT = (which == 0) ? WqT : (which == 1) ? WkT : (which == 2) ? WvT : WoT;
        int idx = (bx % 2304) * 256 + threadIdx.x;  // 768*768
        int n = idx / DM, kd = idx % DM;
        float val;
        if (which < 3) { int h = n >> 6, kk = n & 63; val = W[(h * DM + kd) * DK + kk]; }
        else          { val = W[kd * DM + n]; }
        WT[idx] = bf16rne(val);
    } else {
        int t = (bx - 9216) * 256 + threadIdx.x;  // 1,048,576 threads
        const int4* mp = (const int4*)mask;
        int4 a = mp[2 * t], b = mp[2 * t + 1];
        unsigned int by =
            (a.x != 0 ? 1u : 0u)  | (a.y != 0 ? 2u : 0u)  | (a.z != 0 ? 4u : 0u)  | (a.w != 0 ? 8u : 0u) |
            (b.x != 0 ? 16u : 0u) | (b.y != 0 ? 32u : 0u) | (b.z != 0 ? 64u : 0u) | (b.w != 0 ? 128u : 0u);
        ((unsigned char*)pm)[t] = (unsigned char)by;
    }
}

// ---------------- GEMM core (m97-style): global_load_lds width-16 staging (bf16 A) ----------------
__device__ __forceinline__ void gemm_core(const unsigned short* __restrict__ A,
                                          const unsigned short* __restrict__ BT,
                                          unsigned short* As, unsigned short* Bs,
                                          f32x4 (&acc)[4][4]) {
    const int tid = threadIdx.x;
    const int lane = tid & 63, wid = tid >> 6;
    const int ww = wid & 1, wh = wid >> 1;
    const int quad = lane >> 4, l16 = lane & 15;
    const int lr = lane >> 2;        // row within 16-row chunk
    const int lc = (lane & 3) * 8;   // col offset in shorts
    typedef __attribute__((address_space(1))) const unsigned int* gp1;
    typedef __attribute__((address_space(3))) unsigned int* lp3;
    const unsigned short* Ag = A + (size_t)(wid * 32 + lr) * DM + lc;
    const unsigned short* Bg = BT + (size_t)(wid * 32 + lr) * DM + lc;
    unsigned short* Al = &As[wid * 32 * 32];
    unsigned short* Bl = &Bs[wid * 32 * 32];
    for (int kt = 0; kt < DM; kt += 32) {
        __syncthreads();
        __builtin_amdgcn_global_load_lds((gp1)(const void*)(Ag + kt),            (lp3)(void*)Al,             16, 0, 0);
        __builtin_amdgcn_global_load_lds((gp1)(const void*)(Ag + 16 * DM + kt),  (lp3)(void*)(Al + 16 * 32), 16, 0, 0);
        __builtin_amdgcn_global_load_lds((gp1)(const void*)(Bg + kt),            (lp3)(void*)Bl,             16, 0, 0);
        __builtin_amdgcn_global_load_lds((gp1)(const void*)(Bg + 16 * DM + kt),  (lp3)(void*)(Bl + 16 * 32), 16, 0, 0);
        __syncthreads();
        short8 af[4], bf[4];
#pragma unroll
        for (int i = 0; i < 4; ++i) af[i] = *(const short8*)&As[(wh * 64 + i * 16 + l16) * 32 + quad * 8];
#pragma unroll
        for (int j = 0; j < 4; ++j) bf[j] = *(const short8*)&Bs[(ww * 64 + j * 16 + l16) * 32 + quad * 8];
#pragma unroll
        for (int i = 0; i < 4; ++i)
#pragma unroll
            for (int j = 0; j < 4; ++j)
                acc[i][j] = __builtin_amdgcn_mfma_f32_16x16x32_bf16(af[i], bf[j], acc[i][j], 0, 0, 0);
    }
}

// ---------------- GEMM core, f32 A input: reg-stage + cvt_pk + ds_write_b128 ----------------
// Eliminates the separate cvt pass: converts q/k/v fp32 -> bf16 while staging A tiles.
__device__ __forceinline__ void gemm_core_f32A(const float* __restrict__ A,
                                               const unsigned short* __restrict__ BT,
                                               unsigned short* As, unsigned short* Bs,
                                               f32x4 (&acc)[4][4]) {
    const int tid = threadIdx.x;
    const int lane = tid & 63, wid = tid >> 6;
    const int ww = wid & 1, wh = wid >> 1;
    const int quad = lane >> 4, l16 = lane & 15;
    const int lr = lane >> 2;
    const int lc = (lane & 3) * 8;
    typedef __attribute__((address_space(1))) const unsigned int* gp1;
    typedef __attribute__((address_space(3))) unsigned int* lp3;
    const float* Ag0 = A + (size_t)(wid * 32 + lr) * DM + lc;
    const float* Ag1 = A + (size_t)(wid * 32 + 16 + lr) * DM + lc;
    const unsigned short* Bg = BT + (size_t)(wid * 32 + lr) * DM + lc;
    unsigned short* Al = &As[wid * 32 * 32];
    unsigned short* Bl = &Bs[wid * 32 * 32];
    for (int kt = 0; kt < DM; kt += 32) {
        __syncthreads();
        __builtin_amdgcn_global_load_lds((gp1)(const void*)(Bg + kt),            (lp3)(void*)Bl,             16, 0, 0);
        __builtin_amdgcn_global_load_lds((gp1)(const void*)(Bg + 16 * DM + kt),  (lp3)(void*)(Bl + 16 * 32), 16, 0, 0);
        float4 x0 = *(const float4*)(Ag0 + kt), x1 = *(const float4*)(Ag0 + kt + 4);
        float4 y0 = *(const float4*)(Ag1 + kt), y1 = *(const float4*)(Ag1 + kt + 4);
        u32x4 ua, ub;
        ua[0] = cvtpk(x0.x, x0.y); ua[1] = cvtpk(x0.z, x0.w);
        ua[2] = cvtpk(x1.x, x1.y); ua[3] = cvtpk(x1.z, x1.w);
        ub[0] = cvtpk(y0.x, y0.y); ub[1] = cvtpk(y0.z, y0.w);
        ub[2] = cvtpk(y1.x, y1.y); ub[3] = cvtpk(y1.z, y1.w);
        *(u32x4*)&Al[lr * 32 + lc] = ua;
        *(u32x4*)&Al[(16 + lr) * 32 + lc] = ub;
        __syncthreads();
        short8 af[4], bf[4];
#pragma unroll
        for (int i = 0; i < 4; ++i) af[i] = *(const short8*)&As[(wh * 64 + i * 16 + l16) * 32 + quad * 8];
#pragma unroll
        for (int j = 0; j < 4; ++j) bf[j] = *(const short8*)&Bs[(ww * 64 + j * 16 + l16) * 32 + quad * 8];
#pragma unroll
        for (int i = 0; i < 4; ++i)
#pragma unroll
            for (int j = 0; j < 4; ++j)
                acc[i][j] = __builtin_amdgcn_mfma_f32_16x16x32_bf16(af[i], bf[j], acc[i][j], 0, 0, 0);
    }
}

// ---------------- projections: q,k -> [M, H*64] bf16 ; v -> vhT[b,h,d,s'] bf16 (key-permuted) ----------------
// vhT key index is bit-permuted within each 64-group: s bits [k5 k4 k3 k2 | k1 k0] stored at
// position [k5 k3 k2 k4 | k1 k0], so attn's PV B-operand alignment needs NO staging shuffle.
__global__ __launch_bounds__(256) void proj_gemm(
        const float* __restrict__ qf32, const float* __restrict__ kf32,
        const float* __restrict__ vf32,
        const unsigned short* __restrict__ WqT, const unsigned short* __restrict__ WkT,
        const unsigned short* __restrict__ WvT,
        unsigned short* __restrict__ qh, unsigned short* __restrict__ kh,
        unsigned short* __restrict__ vhT) {
    __shared__ __align__(16) unsigned short As[128 * 32];
    __shared__ __align__(16) unsigned short Bs[128 * 32];
    const int z = blockIdx.z;
    const float* A = (z == 0) ? qf32 : (z == 1) ? kf32 : vf32;
    const unsigned short* BT = (z == 0) ? WqT : (z == 1) ? WkT : WvT;
    f32x4 acc[4][4] = {};
    gemm_core_f32A(A + (size_t)blockIdx.x * 128 * DM, BT + (size_t)blockIdx.y * 128 * DM, As, Bs, acc);

    const int tid = threadIdx.x;
    const int lane = tid & 63, wid = tid >> 6;
    const int ww = wid & 1, wh = wid >> 1;
    const int quad = lane >> 4, l16 = lane & 15;
    const int row0 = blockIdx.x * 128 + wh * 64;
    const int col0 = blockIdx.y * 128 + ww * 64;
    if (z < 2) {
        unsigned short* C = z ? kh : qh;
#pragma unroll
        for (int i = 0; i < 4; ++i)
#pragma unroll
            for (int j = 0; j < 4; ++j)
#pragma unroll
                for (int r = 0; r < 4; ++r)
                    C[(size_t)(row0 + i * 16 + quad * 4 + r) * DM + col0 + j * 16 + l16] = bf16rne(acc[i][j][r]);
    } else {
#pragma unroll
        for (int i = 0; i < 4; ++i)
#pragma unroll
            for (int j = 0; j < 4; ++j) {
                int row = row0 + i * 16 + quad * 4;  // = b*2048 + s, 4 consecutive s
                int col = col0 + j * 16 + l16;       // = h*64 + d
                int bb = row >> 11, s = row & 2047;
                int hh = col >> 6, d = col & 63;
                // key bit-permute within 64-group (preserves low 2 bits -> uint2 write stays contiguous)
                int g = (s >> 2) & 15;
                int pg = (g & 8) | ((g & 3) << 1) | ((g & 4) >> 2);
                int sp = (s & ~63) | (pg << 2) | (s & 3);
                uint32_t lo = (uint32_t)bf16rne(acc[i][j][0]) | ((uint32_t)bf16rne(acc[i][j][1]) << 16);
                uint32_t hi = (uint32_t)bf16rne(acc[i][j][2]) | ((uint32_t)bf16rne(acc[i][j][3]) << 16);
                uint2 o = make_uint2(lo, hi);
                *(uint2*)&vhT[(size_t)((bb * NH + hh) * DK + d) * S_LEN + sp] = o;
            }
    }
}

// ---------------- flash attention: swapped QK^T, lane-local P, XOR-swizzled 128B-row LDS ----------------
// QK^T as mfma(K,Q) => C[key][q], q = lane&15, key = 16*cb + 4*quad + r. V comes pre-permuted
// from proj_gemm so PV B-operand is exactly the in-lane packed P words. K/V LDS tiles are
// [64 rows][64 shorts] (128B rows) with 16B-slot XOR swizzle (slot ^= row&7) on write AND read.
__global__ __launch_bounds__(256) void attn_kernel(
        const unsigned short* __restrict__ qh, const unsigned short* __restrict__ kh,
        const unsigned short* __restrict__ vhT, const uint32_t* __restrict__ pm,
        unsigned short* __restrict__ pob, float* __restrict__ lsb) {
    const int qt = blockIdx.x, h = blockIdx.y;
    const int b = blockIdx.z >> 1, ks = blockIdx.z & 1;
    const int tid = threadIdx.x, w = tid >> 6, lane = tid & 63;
    const int quad = lane >> 4, l16 = lane & 15;
    __shared__ __align__(16) unsigned short SMEM[2 * 64 * 64];  // Ks | Vs ; reused as Os in epilogue
    unsigned short* Ks = SMEM;
    unsigned short* Vs = SMEM + 64 * 64;

    const int qrow0 = qt * 128 + w * 32;
    short8 qf[2][2];
#pragma unroll
    for (int mi = 0; mi < 2; ++mi) {
        const size_t qbase = (size_t)(b * S_LEN + qrow0 + mi * 16 + l16) * DM + h * DK;
        qf[mi][0] = *(const short8*)&qh[qbase + quad * 8];
        qf[mi][1] = *(const short8*)&qh[qbase + 32 + quad * 8];
    }
    // ones A-frag (only row m=0 is 1.0): lsum = ones x P, lands in row 0 (quad0 lanes)
    short8 of = {};
    if (l16 == 0) {
#pragma unroll
        for (int j = 0; j < 8; ++j) of[j] = (short)0x3F80;
    }

    f32x4 out_t[2][4] = {};  // [mi][c2]: C[d][q], d = c2*16 + quad*4 + r, q = l16
    f32x4 outl[2] = {};

    // staging: 256 threads, 64 rows x 64 cols, 32B/thread
    const int srow = tid >> 2, scol = (tid & 3) << 4;
    const int ssw = (srow & 7) << 3;                 // XOR swizzle, in shorts (16B slots)
    const int sc0 = srow * 64 + (scol ^ ssw);
    const int sc1 = srow * 64 + ((scol + 8) ^ ssw);
    const unsigned short* Kg = kh + (size_t)b * S_LEN * DM + h * DK;
    const unsigned short* Vg = vhT + (size_t)((b * NH + h) * DK) * S_LEN;
    const float SCL = 0.18033688011112042f;  // 0.125 * log2(e)
    const float FM = 12.0f;                  // fixed exponent offset (softmax scale-invariant)
    const int kt0 = ks * (S_LEN / 2);

    short8 kr0, kr1, vr0, vr1;
    // prologue prefetch (T14): tile kt0
    kr0 = *(const short8*)&Kg[(size_t)(kt0 + srow) * DM + scol];
    kr1 = *(const short8*)&Kg[(size_t)(kt0 + srow) * DM + scol + 8];
    vr0 = *(const short8*)&Vg[(size_t)srow * S_LEN + kt0 + scol];
    vr1 = *(const short8*)&Vg[(size_t)srow * S_LEN + kt0 + scol + 8];

    for (int kt = kt0; kt < kt0 + S_LEN / 2; kt += 64) {
        __syncthreads();  // all waves done reading previous tile
        *(short8*)&Ks[sc0] = kr0;
        *(short8*)&Ks[sc1] = kr1;
        *(short8*)&Vs[sc0] = vr0;
        *(short8*)&Vs[sc1] = vr1;
        __syncthreads();  // tile visible
        {   // prefetch next tile (last-iter reads stay inside workspace; values unused)
            const int kn = kt + 64;
            kr0 = *(const short8*)&Kg[(size_t)(kn + srow) * DM + scol];
            kr1 = *(const short8*)&Kg[(size_t)(kn + srow) * DM + scol + 8];
            vr0 = *(const short8*)&Vg[(size_t)srow * S_LEN + kn + scol];
            vr1 = *(const short8*)&Vg[(size_t)srow * S_LEN + kn + scol + 8];
        }
        uint2 mw[2];
#pragma unroll
        for (int mi = 0; mi < 2; ++mi)
            mw[mi] = *(const uint2*)&pm[(size_t)(b * S_LEN + qrow0 + mi * 16 + l16) * 64 + (kt >> 5)];

        // QK^T (swapped) + exp + mask + in-lane pack to PV B-frag words
        u32x4 pf32[2][2];
#pragma unroll
        for (int cb = 0; cb < 4; ++cb) {
            const int krw = cb * 16 + l16, ksw = (krw & 7) << 3;
            short8 kf0 = *(const short8*)&Ks[krw * 64 + ((quad * 8) ^ ksw)];
            short8 kf1 = *(const short8*)&Ks[krw * 64 + ((32 + quad * 8) ^ ksw)];
#pragma unroll
            for (int mi = 0; mi < 2; ++mi) {
                f32x4 zz = {0.f, 0.f, 0.f, 0.f};
                zz = __builtin_amdgcn_mfma_f32_16x16x32_bf16(kf0, qf[mi][0], zz, 0, 0, 0);
                zz = __builtin_amdgcn_mfma_f32_16x16x32_bf16(kf1, qf[mi][1], zz, 0, 0, 0);
                uint32_t mword = (cb & 2) ? mw[mi].y : mw[mi].x;
                float e[4];
#pragma unroll
                for (int r = 0; r < 4; ++r) {
                    float ev = __builtin_amdgcn_exp2f(fmaf(zz[r], SCL, -FM));
                    int32_t mneg = __builtin_amdgcn_sbfe((int32_t)mword, ((cb & 1) << 4) + quad * 4 + r, 1);
                    e[r] = __uint_as_float(__float_as_uint(ev) & (uint32_t)mneg);
                }
                pf32[mi][cb >> 1][(cb & 1) * 2 + 0] = cvtpk(e[0], e[1]);
                pf32[mi][cb >> 1][(cb & 1) * 2 + 1] = cvtpk(e[2], e[3]);
            }
        }
        short8 pf[2][2];
#pragma unroll
        for (int mi = 0; mi < 2; ++mi) {
            pf[mi][0] = __builtin_bit_cast(short8, pf32[mi][0]);
            pf[mi][1] = __builtin_bit_cast(short8, pf32[mi][1]);
        }

        __builtin_amdgcn_s_setprio(1);
#pragma unroll
        for (int c2 = 0; c2 < 4; ++c2) {
            const int vrw = c2 * 16 + l16, vsw = (vrw & 7) << 3;
            short8 vf0 = *(const short8*)&Vs[vrw * 64 + ((quad * 8) ^ vsw)];
            short8 vf1 = *(const short8*)&Vs[vrw * 64 + ((32 + quad * 8) ^ vsw)];
#pragma unroll
            for (int mi = 0; mi < 2; ++mi) {
                out_t[mi][c2] = __builtin_amdgcn_mfma_f32_16x16x32_bf16(vf0, pf[mi][0], out_t[mi][c2], 0, 0, 0);
                out_t[mi][c2] = __builtin_amdgcn_mfma_f32_16x16x32_bf16(vf1, pf[mi][1], out_t[mi][c2], 0, 0, 0);
            }
        }
#pragma unroll
        for (int mi = 0; mi < 2; ++mi) {
            outl[mi] = __builtin_amdgcn_mfma_f32_16x16x32_bf16(of, pf[mi][0], outl[mi], 0, 0, 0);
            outl[mi] = __builtin_amdgcn_mfma_f32_16x16x32_bf16(of, pf[mi][1], outl[mi], 0, 0, 0);
        }
        __builtin_amdgcn_s_setprio(0);
    }

    const int pz = b * 2 + ks;
    if (quad == 0) {
#pragma unroll
        for (int mi = 0; mi < 2; ++mi)
            lsb[((size_t)pz * NH + h) * S_LEN + qrow0 + mi * 16 + l16] = outl[mi][0];
    }

    // epilogue: transpose out via per-wave LDS region (reuse SMEM, swizzled), coalesced stores
    __syncthreads();  // all waves done with Ks/Vs
    unsigned short* Os = SMEM + w * 2048;  // 32 rows x 64 shorts per wave
#pragma unroll
    for (int mi = 0; mi < 2; ++mi) {
        const int orow = mi * 16 + l16, osw = (orow & 7) << 3;
#pragma unroll
        for (int c2 = 0; c2 < 4; ++c2) {
            uint2 pw2;
            pw2.x = cvtpk(out_t[mi][c2][0], out_t[mi][c2][1]);
            pw2.y = cvtpk(out_t[mi][c2][2], out_t[mi][c2][3]);
            *(uint2*)&Os[orow * 64 + ((c2 * 16 + quad * 4) ^ osw)] = pw2;
        }
    }
    const int ql = lane >> 1, hf = lane & 1;
    const int qsw = (ql & 7) << 3;
    const int qg = qrow0 + ql;
    const size_t orowg = ((size_t)pz * S_LEN + qg) * DM + h * DK + hf * 32;
#pragma unroll
    for (int k2 = 0; k2 < 4; ++k2)
        *(short8*)&pob[orowg + k2 * 8] = *(const short8*)&Os[ql * 64 + ((hf * 32 + k2 * 8) ^ qsw)];
}

// ---------------- merge the two K-chunk partials -> ao bf16 ----------------
__global__ __launch_bounds__(256) void merge_kernel(const unsigned short* __restrict__ pob,
                                                    const float* __restrict__ lsb,
                                                    unsigned short* __restrict__ ao) {
    int t = blockIdx.x * 256 + threadIdx.x;   // 4096*192 threads, 4 elems each
    int sg = t / 192;                          // b*S + s
    int c = (t - sg * 192) * 4;                // col in [0,768)
    int b = sg >> 11, s = sg & 2047, h = c >> 6;
    float l = lsb[((size_t)(b * 2) * NH + h) * S_LEN + s] +
              lsb[((size_t)(b * 2 + 1) * NH + h) * S_LEN + s];
    float rl = 1.f / fmaxf(l, 1e-37f);
    uint2 a0 = *(const uint2*)&pob[((size_t)(b * 2) * S_LEN + s) * DM + c];
    uint2 a1 = *(const uint2*)&pob[((size_t)(b * 2 + 1) * S_LEN + s) * DM + c];
    float f0 = __uint_as_float((a0.x & 0xFFFFu) << 16) + __uint_as_float((a1.x & 0xFFFFu) << 16);
    float f1 = __uint_as_float((a0.x >> 16) << 16)     + __uint_as_float((a1.x >> 16) << 16);
    float f2 = __uint_as_float((a0.y & 0xFFFFu) << 16) + __uint_as_float((a1.y & 0xFFFFu) << 16);
    float f3 = __uint_as_float((a0.y >> 16) << 16)     + __uint_as_float((a1.y >> 16) << 16);
    uint32_t lo = (uint32_t)bf16rne(f0 * rl) | ((uint32_t)bf16rne(f1 * rl) << 16);
    uint32_t hi = (uint32_t)bf16rne(f2 * rl) | ((uint32_t)bf16rne(f3 * rl) << 16);
    uint2 o = make_uint2(lo, hi);
    *(uint2*)&ao[(size_t)sg * DM + c] = o;
}

// ---------------- output projection: fp32 store ----------------
__global__ __launch_bounds__(256) void out_gemm(const unsigned short* __restrict__ ao,
                                                const unsigned short* __restrict__ WoT,
                                                float* __restrict__ C) {
    __shared__ __align__(16) unsigned short As[128 * 32];
    __shared__ __align__(16) unsigned short Bs[128 * 32];
    f32x4 acc[4][4] = {};
    gemm_core(ao + (size_t)blockIdx.x * 128 * DM, WoT + (size_t)blockIdx.y * 128 * DM, As, Bs, acc);
    const int tid = threadIdx.x;
    const int lane = tid & 63, wid = tid >> 6;
    const int ww = wid & 1, wh = wid >> 1;
    const int quad = lane >> 4, l16 = lane & 15;
    const int row0 = blockIdx.x * 128 + wh * 64;
    const int col0 = blockIdx.y * 128 + ww * 64;
#pragma unroll
    for (int i = 0; i < 4; ++i)
#pragma unroll
        for (int j = 0; j < 4; ++j)
#pragma unroll
            for (int r = 0; r < 4; ++r)
                C[(size_t)(row0 + i * 16 + quad * 4 + r) * DM + col0 + j * 16 + l16] = acc[i][j][r];
}

extern "C" void kernel_launch(void* const* d_in, const int* in_sizes, int n_in,
                              void* d_out, int out_size, void* d_ws, size_t ws_size,
                              hipStream_t stream) {
    const float* q = (const float*)d_in[0];
    const float* k = (const float*)d_in[1];
    const float* v = (const float*)d_in[2];
    const int* mask = (const int*)d_in[3];
    const float* Wq = (const float*)d_in[4];
    const float* Wk = (const float*)d_in[5];
    const float* Wv = (const float*)d_in[6];
    const float* Wo = (const float*)d_in[7];
    float* out = (float*)d_out;

    char* ws = (char*)d_ws;
    size_t off = 0;
    auto alloc = [&](size_t bytes) {
        void* p = ws + off;
        off += (bytes + 255) & ~(size_t)255;
        return p;
    };
    const size_t MAT = (size_t)MROWS * DM * 2;      // 6291456 B
    const size_t WMAT = (size_t)DM * DM * 2;        // 1179648 B
    unsigned short* WqT = (unsigned short*)alloc(WMAT);
    unsigned short* WkT = (unsigned short*)alloc(WMAT);
    unsigned short* WvT = (unsigned short*)alloc(WMAT);
    unsigned short* WoT = (unsigned short*)alloc(WMAT);
    unsigned short* qh  = (unsigned short*)alloc(MAT);
    unsigned short* kh  = (unsigned short*)alloc(MAT);
    unsigned short* vhT = (unsigned short*)alloc(MAT);
    unsigned short* ao  = (unsigned short*)alloc(MAT);
    uint32_t* pmask     = (uint32_t*)alloc((size_t)NB * S_LEN * 64 * 4);
    unsigned short* pob = (unsigned short*)alloc((size_t)4 * S_LEN * DM * 2);  // 12.58 MB
    float* lsb          = (float*)alloc((size_t)4 * NH * S_LEN * 4);

    prep_kernel<<<dim3(9216 + 4096), 256, 0, stream>>>(Wq, Wk, Wv, Wo, mask,
                                                       WqT, WkT, WvT, WoT, pmask);
    proj_gemm<<<dim3(32, 6, 3), 256, 0, stream>>>(q, k, v, WqT, WkT, WvT, qh, kh, vhT);
    attn_kernel<<<dim3(16, 12, 4), 256, 0, stream>>>(qh, kh, vhT, pmask, pob, lsb);
    merge_kernel<<<dim3(3072), 256, 0, stream>>>(pob, lsb, ao);
    out_gemm<<<dim3(32, 6), 256, 0, stream>>>(ao, WoT, out);
}